// Round 16
// baseline (2828.352 us; speedup 1.0000x reference)
//
#include <hip/hip_runtime.h>

typedef unsigned int u32;
typedef int v4i __attribute__((ext_vector_type(4)));

#define T_LEN 2048
#define NEG (-10000.0f)
#define WSCALE 2032.0f
#define HSCALE 127.0f
#define SCALE_INV (1.0f / (2032.0f * 127.0f))

// ---------- helpers ----------
__device__ __forceinline__ u32 rdlane_u32(u32 v, int lane) {
#if __has_builtin(__builtin_amdgcn_readlane)
  return (u32)__builtin_amdgcn_readlane((int)v, lane);
#else
  return (u32)__shfl((int)v, lane);
#endif
}

__device__ __forceinline__ float rdlane_f32(float v, int lane) {
  return __builtin_bit_cast(float, rdlane_u32(__builtin_bit_cast(u32, v), lane));
}

// Raw barrier: LDS-drain only, no vmcnt(0) drain.
__device__ __forceinline__ void block_sync_lds() {
  asm volatile("s_waitcnt lgkmcnt(0)" ::: "memory");
  __builtin_amdgcn_s_barrier();
}

// In-wave LDS fence (same-wave DS ops are pipe-ordered).
__device__ __forceinline__ void wave_lds_fence() {
  asm volatile("s_waitcnt lgkmcnt(0)" ::: "memory");
}

// i8 MFMA intrinsic: A-fragments allocate to AGPRs with zero copies.
__device__ __forceinline__ v4i mfma_i8(v4i a, v4i b, v4i c) {
#if __has_builtin(__builtin_amdgcn_mfma_i32_16x16x64_i8)
  return __builtin_amdgcn_mfma_i32_16x16x64_i8(a, b, c, 0, 0, 0);
#else
  v4i d;
  asm("v_mfma_i32_16x16x64_i8 %0, %1, %2, %3"
      : "=&v"(d) : "v"(a), "v"(b), "v"(c));
  return d;
#endif
}

// ---------- kernel 1: pack Whh into GATE-INTERLEAVED MFMA A-fragments ----------
// dword idx = d*65536 + rt*1024 + kt*256 + lane*4 + e  (v4i per lane)
// Tile-row i = lane&15 -> matvec row (i&3)*256 + rt*4 + (i>>2)
// k = kt*64 + (lane>>4)*16 + e*4 + b   (A-layout HW-verified rounds 13-15)
__global__ void pack_whh_i8(const float* __restrict__ Wf,
                            const float* __restrict__ Wb,
                            u32* __restrict__ WP) {
  int idx = blockIdx.x * 256 + threadIdx.x;   // < 131072
  int e  = idx & 3;
  int l  = (idx >> 2) & 63;
  int kt = (idx >> 8) & 3;
  int rt = (idx >> 10) & 63;
  int d  = (idx >> 16) & 1;
  int i   = l & 15;
  int row = (i & 3) * 256 + rt * 4 + (i >> 2);
  int k0  = kt * 64 + (l >> 4) * 16 + e * 4;
  const float* W = d ? Wb : Wf;
  u32 p = 0;
  #pragma unroll
  for (int b = 0; b < 4; ++b) {
    float x = W[row * 256 + k0 + b];
    int q = (int)rintf(fminf(fmaxf(x * WSCALE, -127.f), 127.f));
    p |= (u32)(q & 255) << (8 * b);
  }
  WP[idx] = p;
}

// ---------- kernel 2: embedding gather ----------
__global__ void gather_kernel(const int* __restrict__ words,
                              const float* __restrict__ embed,
                              float* __restrict__ xs) {
  int t = blockIdx.x;
  int k = threadIdx.x;
  xs[t * 256 + k] = embed[(size_t)words[t] * 256 + k];
}

// ---------- kernel 3: XW[d][t][c][G] = xs[t]·Wih_d[G*256+c] + bih + bhh ----------
__global__ __launch_bounds__(256) void gemm_xw(
    const float* __restrict__ xs,
    const float* __restrict__ Wf, const float* __restrict__ Wb,
    const float* __restrict__ bihf, const float* __restrict__ bhhf,
    const float* __restrict__ bihb, const float* __restrict__ bhhb,
    float* __restrict__ XW) {
  __shared__ float lx[32 * 256];
  __shared__ float lw[32 * 132];
  const int tid = threadIdx.x;
  const int t0 = blockIdx.x * 32;
  const int g0 = blockIdx.y * 128;
  const int d  = blockIdx.z;
  const float* W = d ? Wb : Wf;

  #pragma unroll 4
  for (int r = 0; r < 32; ++r) lx[r * 256 + tid] = xs[(t0 + r) * 256 + tid];

  const int tg = tid & 31, tt = tid >> 5;
  float acc[4][4] = {};

  for (int kc = 0; kc < 8; ++kc) {
    __syncthreads();
    #pragma unroll
    for (int r2 = 0; r2 < 16; ++r2) {
      int gg = r2 * 8 + (tid >> 5);
      int k  = tid & 31;
      lw[k * 132 + gg] = W[(g0 + gg) * 256 + kc * 32 + k];
    }
    __syncthreads();
    #pragma unroll
    for (int k = 0; k < 32; ++k) {
      float4 wv = *(const float4*)&lw[k * 132 + tg * 4];
      #pragma unroll
      for (int a = 0; a < 4; ++a) {
        float xa = lx[(tt * 4 + a) * 256 + kc * 32 + k];
        acc[a][0] = fmaf(xa, wv.x, acc[a][0]);
        acc[a][1] = fmaf(xa, wv.y, acc[a][1]);
        acc[a][2] = fmaf(xa, wv.z, acc[a][2]);
        acc[a][3] = fmaf(xa, wv.w, acc[a][3]);
      }
    }
  }
  const float* bih = d ? bihb : bihf;
  const float* bhh = d ? bhhb : bhhf;
  int gcol = g0 + tg * 4;
  float bb[4];
  #pragma unroll
  for (int j = 0; j < 4; ++j) bb[j] = bih[gcol + j] + bhh[gcol + j];
  #pragma unroll
  for (int a = 0; a < 4; ++a) {
    size_t trow = (size_t)d * T_LEN + t0 + tt * 4 + a;
    #pragma unroll
    for (int j = 0; j < 4; ++j) {
      int g = gcol + j;
      XW[trow * 1024 + (g & 255) * 4 + (g >> 8)] = acc[a][j] + bb[j];
    }
  }
}

// ---------- kernel 4: sequential bidirectional LSTM via i8 MFMA ----------
// grid = 2 (d), block = 1024 (16 waves, 4/SIMD — 4-way interleave hides the
// exchange/tail/barrier latency that round 15's 2-wave/SIMD config exposed).
// Wave w owns tiles rt = w*4..w*4+3 (cells w*16..w*16+15); A = 16 v4i/lane
// in AGPRs via the intrinsic. Gate-interleaved D: col 0 at lane 16g = all 4
// gates of cell rt*4+g. Intra-wave GT exchange (no barrier); consumers =
// lanes<16/wave; one block barrier per step (H8 double-buffered).
// LDS dwords: [0,128) H8 2 bufs x 256 B; [128,1152) GT 16 waves x 256 B.
__global__ void __launch_bounds__(1024)
lstm_seq(
    const float* __restrict__ XW, float* __restrict__ HS,
    const u32* __restrict__ wpack,
    const float* __restrict__ h0, const float* __restrict__ c0) {
  __shared__ u32 smem[1152];
  const int t = threadIdx.x;
  const int d = blockIdx.x;
  const int lane = t & 63;
  const int w = t >> 6;

  v4i A[4][4];
  {
    const v4i* AP = (const v4i*)wpack;
    #pragma unroll
    for (int j = 0; j < 4; ++j) {
      #pragma unroll
      for (int kt = 0; kt < 4; ++kt)
        A[j][kt] = AP[((d * 64 + w * 4 + j) * 4 + kt) * 64 + lane];
    }
  }

  unsigned char* H8b = (unsigned char*)smem;          // 2 x 256 B
  char* GTw = (char*)smem + 512 + w * 256;            // this wave's strip
  const bool cons = (lane < 16);
  const int c = w * 16 + (lane & 15);                 // consumer's cell

  float cst = 0.f, h = 0.f;
  if (cons) {
    cst = c0[d * 256 + c];
    h   = h0[d * 256 + c];
    int hi = (int)rintf(fminf(fmaxf(h, -1.f), 1.f) * HSCALE);
    H8b[c] = (unsigned char)(hi & 255);
  }
  block_sync_lds();

  const char* sb = (const char*)smem;
  const int gq = (lane >> 4) * 16;                    // B k-group byte offset
  char* gtp = GTw + gq;                               // producer base (+j*64)
  const char* grd = GTw + (lane & 15) * 16;           // consumer read addr
  const v4i vzero = {0, 0, 0, 0};

  const int delta = d ? -1024 : 1024;
  const float* xwp = XW + ((size_t)d * T_LEN + (d ? (T_LEN - 1) : 0)) * 1024 + c * 4;
  float* hsp = HS + ((size_t)d * T_LEN + (d ? (T_LEN - 1) : 0)) * 256 + c;
  const int hdelta = d ? -256 : 256;
  float4 xc = make_float4(0.f, 0.f, 0.f, 0.f);
  if (cons) xc = *(const float4*)xwp;

  for (int s = 0; s < T_LEN; ++s) {
    float4 xn = make_float4(0.f, 0.f, 0.f, 0.f);
    if (cons && s < T_LEN - 1) { xwp += delta; xn = *(const float4*)xwp; }

    const char* hp = sb + (s & 1) * 256 + gq;         // broadcast per group
    v4i B0 = *(const v4i*)(hp);
    v4i B1 = *(const v4i*)(hp + 64);
    v4i B2 = *(const v4i*)(hp + 128);
    v4i B3 = *(const v4i*)(hp + 192);

    const bool prod = ((lane & 15) == 0);
    #pragma unroll
    for (int j = 0; j < 4; ++j) {
      v4i acc = mfma_i8(A[j][0], B0, vzero);
      acc = mfma_i8(A[j][1], B1, acc);
      acc = mfma_i8(A[j][2], B2, acc);
      acc = mfma_i8(A[j][3], B3, acc);
      if (prod) *(v4i*)(gtp + j * 64) = acc;          // write as soon as ready
    }
    wave_lds_fence();                                 // same-wave exchange

    if (cons) {
      v4i gv = *(const v4i*)grd;                      // (i,f,g,o) raw dots
      float gi = fmaf((float)gv.x, SCALE_INV, xc.x);
      float gf = fmaf((float)gv.y, SCALE_INV, xc.y);
      float gc = fmaf((float)gv.z, SCALE_INV, xc.z);
      float go = fmaf((float)gv.w, SCALE_INV, xc.w);
      gi = 1.f / (1.f + __expf(-gi));
      gf = 1.f / (1.f + __expf(-gf));
      go = 1.f / (1.f + __expf(-go));
      gc = 1.f - 2.f / (__expf(2.f * gc) + 1.f);      // tanh
      cst = gf * cst + gi * gc;
      float th = 1.f - 2.f / (__expf(2.f * cst) + 1.f);
      h = go * th;
      *hsp = h;                                       // no reader in-kernel
      hsp += hdelta;
      int hi = (int)rintf(h * HSCALE);                // |h|<1
      H8b[((s + 1) & 1) * 256 + c] = (unsigned char)(hi & 255);
    }
    block_sync_lds();                                 // ONE barrier per step
    xc = xn;
  }
}

// ---------- kernel 5: feats[t][n] = [hs_f ; hs_b]·W_out[n] + b_out[n] ----------
__global__ void feats_kernel(const float* __restrict__ hs,
                             const float* __restrict__ wout,
                             const float* __restrict__ bout,
                             float* __restrict__ feats) {
  __shared__ float lf[16 * 257];
  __shared__ float lb[16 * 257];
  const int tid = threadIdx.x;   // 128
  const int t0 = blockIdx.x * 16;
  for (int i = tid; i < 16 * 256; i += 128) {
    int r = i >> 8, k = i & 255;
    lf[r * 257 + k] = hs[(size_t)(t0 + r) * 256 + k];
    lb[r * 257 + k] = hs[(size_t)T_LEN * 256 + (size_t)(t0 + r) * 256 + k];
  }
  __syncthreads();
  const int tl = tid >> 3, n = tid & 7;
  if (n < 7) {
    float acc = bout[n];
    #pragma unroll 8
    for (int k = 0; k < 256; ++k) acc = fmaf(lf[tl * 257 + k], wout[n * 512 + k], acc);
    #pragma unroll 8
    for (int k = 0; k < 256; ++k) acc = fmaf(lb[tl * 257 + k], wout[n * 512 + 256 + k], acc);
    feats[(t0 + tl) * 7 + n] = acc;
  }
}

// ---------- kernel 6: Viterbi decode ----------
__global__ __launch_bounds__(256) void viterbi_kernel(
    const float* __restrict__ feats,
    const float* __restrict__ trans,
    float* __restrict__ out) {
  extern __shared__ char vsm[];
  float*         fe = (float*)vsm;                       // [T_LEN*7]
  unsigned char* bp = (unsigned char*)(vsm + 57344);     // [T_LEN][8]
  unsigned char* G  = (unsigned char*)(vsm + 73728);     // [32][8]
  unsigned char* bt = (unsigned char*)(vsm + 73984);     // [32]
  const int tid = threadIdx.x;

  for (int i = tid; i < T_LEN * 7; i += 256) fe[i] = feats[i];
  __syncthreads();

  if (tid < 64) {
    const int j  = tid;
    const int jc = (j < 7) ? j : 0;
    float Trow[7];
    #pragma unroll
    for (int i = 0; i < 7; ++i) Trow[i] = trans[jc * 7 + i];
    float fv = (j == 5) ? 0.0f : NEG;    // START = 5
    for (int t = 0; t < T_LEN; ++t) {
      float f0 = rdlane_f32(fv, 0), f1 = rdlane_f32(fv, 1), f2 = rdlane_f32(fv, 2),
            f3 = rdlane_f32(fv, 3), f4 = rdlane_f32(fv, 4), f5 = rdlane_f32(fv, 5),
            f6 = rdlane_f32(fv, 6);
      float v0 = f0 + Trow[0], v1 = f1 + Trow[1], v2 = f2 + Trow[2],
            v3 = f3 + Trow[3], v4 = f4 + Trow[4], v5 = f5 + Trow[5],
            v6 = f6 + Trow[6];
      bool c01 = v0 >= v1;  float m01 = c01 ? v0 : v1;  int i01 = c01 ? 0 : 1;
      bool c23 = v2 >= v3;  float m23 = c23 ? v2 : v3;  int i23 = c23 ? 2 : 3;
      bool c45 = v4 >= v5;  float m45 = c45 ? v4 : v5;  int i45 = c45 ? 4 : 5;
      bool cA  = m01 >= m23; float mA = cA ? m01 : m23; int iA = cA ? i01 : i23;
      bool cB  = m45 >= v6;  float mB = cB ? m45 : v6;  int iB = cB ? i45 : 6;
      bool cF  = mA >= mB;   float best = cF ? mA : mB; int bi = cF ? iA : iB;
      if (j < 7) bp[t * 8 + j] = (unsigned char)bi;
      fv = best + fe[t * 7 + jc];
    }
    float term = fv + trans[42 + jc];    // transitions[END=6][j]
    float best = rdlane_f32(term, 0); int btag = 0;
    #pragma unroll
    for (int i = 1; i < 7; ++i) {
      float ti = rdlane_f32(term, i);
      if (ti > best) { best = ti; btag = i; }
    }
    if (j == 0) {
      out[0] = best;
      bt[31] = (unsigned char)btag;      // tag at t = 2047
    }
  }
  __syncthreads();

  // Phase A: per-segment composed maps (32 segments x 7 entry tags)
  {
    const int s = tid >> 3, j = tid & 7;
    if (s < 32 && j < 7) {
      int g = j;
      for (int t = s * 64 + 63; t >= s * 64; --t) g = bp[t * 8 + g];
      G[s * 8 + j] = (unsigned char)g;
    }
  }
  __syncthreads();

  // Phase B: boundary tags, serial over 32 segments
  if (tid == 0) {
    int x = bt[31];
    for (int s = 31; s >= 1; --s) { x = G[s * 8 + x]; bt[s - 1] = (unsigned char)x; }
  }
  __syncthreads();

  // Phase C: parallel rewalk, one lane per segment
  if (tid < 32) {
    const int s = tid;
    int tag = bt[s];
    for (int t = s * 64 + 63; t >= s * 64; --t) {
      out[1 + t] = (float)tag;
      tag = bp[t * 8 + tag];
    }
  }
}

// ---------- host ----------
extern "C" void kernel_launch(void* const* d_in, const int* in_sizes, int n_in,
                              void* d_out, int out_size, void* d_ws, size_t ws_size,
                              hipStream_t stream) {
  const int*   words = (const int*)d_in[0];
  const float* embed = (const float*)d_in[1];
  const float* Wih_f = (const float*)d_in[2];
  const float* Whh_f = (const float*)d_in[3];
  const float* bih_f = (const float*)d_in[4];
  const float* bhh_f = (const float*)d_in[5];
  const float* Wih_b = (const float*)d_in[6];
  const float* Whh_b = (const float*)d_in[7];
  const float* bih_b = (const float*)d_in[8];
  const float* bhh_b = (const float*)d_in[9];
  const float* Wout  = (const float*)d_in[10];
  const float* bout  = (const float*)d_in[11];
  const float* trans = (const float*)d_in[12];
  const float* h0    = (const float*)d_in[13];
  const float* c0    = (const float*)d_in[14];

  float* ws = (float*)d_ws;
  float* XW = ws;                        // 2*2048*1024           = 4,194,304 f
  float* HS = ws + 4194304;              // 2*2048*256            = 1,048,576 f
  float* XS = ws + 5242880;              // 2048*256              =   524,288 f
  float* FE = ws + 5767168;              // 2048*7                =    14,336 f
  u32*   WP = (u32*)(ws + 5781504);      // 131,072 dwords (int8 A-fragments)

  pack_whh_i8<<<512, 256, 0, stream>>>(Whh_f, Whh_b, WP);
  gather_kernel<<<T_LEN, 256, 0, stream>>>(words, embed, XS);
  dim3 ggrid(T_LEN / 32, 1024 / 128, 2);
  gemm_xw<<<ggrid, 256, 0, stream>>>(XS, Wih_f, Wih_b, bih_f, bhh_f, bih_b, bhh_b, XW);
  lstm_seq<<<2, 1024, 0, stream>>>(XW, HS, WP, h0, c0);
  feats_kernel<<<128, 128, 0, stream>>>(HS, Wout, bout, FE);
  viterbi_kernel<<<1, 256, 74048, stream>>>(FE, trans, (float*)d_out);
}

// Round 17
// 2667.929 us; speedup vs baseline: 1.0601x; 1.0601x over previous
//
#include <hip/hip_runtime.h>

typedef unsigned int u32;
typedef int v4i __attribute__((ext_vector_type(4)));

#define T_LEN 2048
#define NEG (-10000.0f)
#define WSCALE 2032.0f
#define HSCALE 127.0f
#define SCALE_INV (1.0f / (2032.0f * 127.0f))

// ---------- helpers ----------
__device__ __forceinline__ u32 rdlane_u32(u32 v, int lane) {
#if __has_builtin(__builtin_amdgcn_readlane)
  return (u32)__builtin_amdgcn_readlane((int)v, lane);
#else
  return (u32)__shfl((int)v, lane);
#endif
}

__device__ __forceinline__ float rdlane_f32(float v, int lane) {
  return __builtin_bit_cast(float, rdlane_u32(__builtin_bit_cast(u32, v), lane));
}

// Raw barrier: LDS-drain only, no vmcnt(0) drain.
__device__ __forceinline__ void block_sync_lds() {
  asm volatile("s_waitcnt lgkmcnt(0)" ::: "memory");
  __builtin_amdgcn_s_barrier();
}

// In-wave LDS fence (same-wave DS ops are pipe-ordered).
__device__ __forceinline__ void wave_lds_fence() {
  asm volatile("s_waitcnt lgkmcnt(0)" ::: "memory");
}

// i8 MFMA intrinsic: A-fragments allocate to AGPRs with zero copies.
__device__ __forceinline__ v4i mfma_i8(v4i a, v4i b, v4i c) {
#if __has_builtin(__builtin_amdgcn_mfma_i32_16x16x64_i8)
  return __builtin_amdgcn_mfma_i32_16x16x64_i8(a, b, c, 0, 0, 0);
#else
  v4i d;
  asm("v_mfma_i32_16x16x64_i8 %0, %1, %2, %3"
      : "=&v"(d) : "v"(a), "v"(b), "v"(c));
  return d;
#endif
}

// ---------- kernel 1: pack Whh into GATE-INTERLEAVED MFMA A-fragments ----------
// dword idx = d*65536 + rt*1024 + kt*256 + lane*4 + e  (v4i per lane)
// Tile-row i = lane&15 -> matvec row (i&3)*256 + rt*4 + (i>>2)
// k = kt*64 + (lane>>4)*16 + e*4 + b   (A-layout HW-verified rounds 13-16)
__global__ void pack_whh_i8(const float* __restrict__ Wf,
                            const float* __restrict__ Wb,
                            u32* __restrict__ WP) {
  int idx = blockIdx.x * 256 + threadIdx.x;   // < 131072
  int e  = idx & 3;
  int l  = (idx >> 2) & 63;
  int kt = (idx >> 8) & 3;
  int rt = (idx >> 10) & 63;
  int d  = (idx >> 16) & 1;
  int i   = l & 15;
  int row = (i & 3) * 256 + rt * 4 + (i >> 2);
  int k0  = kt * 64 + (l >> 4) * 16 + e * 4;
  const float* W = d ? Wb : Wf;
  u32 p = 0;
  #pragma unroll
  for (int b = 0; b < 4; ++b) {
    float x = W[row * 256 + k0 + b];
    int q = (int)rintf(fminf(fmaxf(x * WSCALE, -127.f), 127.f));
    p |= (u32)(q & 255) << (8 * b);
  }
  WP[idx] = p;
}

// ---------- kernel 2: embedding gather ----------
__global__ void gather_kernel(const int* __restrict__ words,
                              const float* __restrict__ embed,
                              float* __restrict__ xs) {
  int t = blockIdx.x;
  int k = threadIdx.x;
  xs[t * 256 + k] = embed[(size_t)words[t] * 256 + k];
}

// ---------- kernel 3: XW[d][t][c][G] = xs[t]·Wih_d[G*256+c] + bih + bhh ----------
__global__ __launch_bounds__(256) void gemm_xw(
    const float* __restrict__ xs,
    const float* __restrict__ Wf, const float* __restrict__ Wb,
    const float* __restrict__ bihf, const float* __restrict__ bhhf,
    const float* __restrict__ bihb, const float* __restrict__ bhhb,
    float* __restrict__ XW) {
  __shared__ float lx[32 * 256];
  __shared__ float lw[32 * 132];
  const int tid = threadIdx.x;
  const int t0 = blockIdx.x * 32;
  const int g0 = blockIdx.y * 128;
  const int d  = blockIdx.z;
  const float* W = d ? Wb : Wf;

  #pragma unroll 4
  for (int r = 0; r < 32; ++r) lx[r * 256 + tid] = xs[(t0 + r) * 256 + tid];

  const int tg = tid & 31, tt = tid >> 5;
  float acc[4][4] = {};

  for (int kc = 0; kc < 8; ++kc) {
    __syncthreads();
    #pragma unroll
    for (int r2 = 0; r2 < 16; ++r2) {
      int gg = r2 * 8 + (tid >> 5);
      int k  = tid & 31;
      lw[k * 132 + gg] = W[(g0 + gg) * 256 + kc * 32 + k];
    }
    __syncthreads();
    #pragma unroll
    for (int k = 0; k < 32; ++k) {
      float4 wv = *(const float4*)&lw[k * 132 + tg * 4];
      #pragma unroll
      for (int a = 0; a < 4; ++a) {
        float xa = lx[(tt * 4 + a) * 256 + kc * 32 + k];
        acc[a][0] = fmaf(xa, wv.x, acc[a][0]);
        acc[a][1] = fmaf(xa, wv.y, acc[a][1]);
        acc[a][2] = fmaf(xa, wv.z, acc[a][2]);
        acc[a][3] = fmaf(xa, wv.w, acc[a][3]);
      }
    }
  }
  const float* bih = d ? bihb : bihf;
  const float* bhh = d ? bhhb : bhhf;
  int gcol = g0 + tg * 4;
  float bb[4];
  #pragma unroll
  for (int j = 0; j < 4; ++j) bb[j] = bih[gcol + j] + bhh[gcol + j];
  #pragma unroll
  for (int a = 0; a < 4; ++a) {
    size_t trow = (size_t)d * T_LEN + t0 + tt * 4 + a;
    #pragma unroll
    for (int j = 0; j < 4; ++j) {
      int g = gcol + j;
      XW[trow * 1024 + (g & 255) * 4 + (g >> 8)] = acc[a][j] + bb[j];
    }
  }
}

// ---------- kernel 4: sequential bidirectional LSTM via i8 MFMA ----------
// grid = 2 (d), block = 256 (4 waves, 1/SIMD — minimal lockstep overhead).
// Wave w owns tiles rt = w*16..w*16+15 (cells w*64..w*64+63, i.e. c = tid).
// A = 64 v4i/lane in AGPRs (256 AGPRs; 512-reg unified budget at 1 wave/EU).
// Producer lane 16q writes tile j's D at GTw + j*64 + q*16 (interleaved into
// the MFMA stream); consumer lane l reads GTw + l*16 (contiguous, one b128);
// tail = 1 cell per lane, all 64 lanes. One block barrier per step.
// LDS dwords: [0,128) H8 2 bufs x 256 B; [128,1152) GT 4 waves x 1024 B.
__global__ void __launch_bounds__(256)
__attribute__((amdgpu_waves_per_eu(1, 1)))
lstm_seq(
    const float* __restrict__ XW, float* __restrict__ HS,
    const u32* __restrict__ wpack,
    const float* __restrict__ h0, const float* __restrict__ c0) {
  __shared__ u32 smem[1152];
  const int t = threadIdx.x;
  const int d = blockIdx.x;
  const int lane = t & 63;
  const int w = t >> 6;
  const int c = t;                                    // one cell per thread

  v4i A[16][4];
  {
    const v4i* AP = (const v4i*)wpack;
    #pragma unroll
    for (int j = 0; j < 16; ++j) {
      #pragma unroll
      for (int kt = 0; kt < 4; ++kt)
        A[j][kt] = AP[((d * 64 + w * 16 + j) * 4 + kt) * 64 + lane];
    }
  }

  unsigned char* H8b = (unsigned char*)smem;          // 2 x 256 B
  char* GTw = (char*)smem + 512 + w * 1024;           // this wave's strip

  float cst = c0[d * 256 + c];
  float h   = h0[d * 256 + c];
  {
    int hi = (int)rintf(fminf(fmaxf(h, -1.f), 1.f) * HSCALE);
    H8b[c] = (unsigned char)(hi & 255);
  }
  block_sync_lds();

  const char* sb = (const char*)smem;
  const int gq = (lane >> 4) * 16;                    // B k-group byte offset
  char* gtp = GTw + gq;                               // producer base (+j*64)
  const char* grd = GTw + lane * 16;                  // consumer read addr
  const bool prod = ((lane & 15) == 0);
  const v4i vzero = {0, 0, 0, 0};

  const int delta = d ? -1024 : 1024;
  const float* xwp = XW + ((size_t)d * T_LEN + (d ? (T_LEN - 1) : 0)) * 1024 + c * 4;
  float* hsp = HS + ((size_t)d * T_LEN + (d ? (T_LEN - 1) : 0)) * 256 + c;
  const int hdelta = d ? -256 : 256;
  float4 xc = *(const float4*)xwp;

  for (int s = 0; s < T_LEN; ++s) {
    float4 xn = make_float4(0.f, 0.f, 0.f, 0.f);
    if (s < T_LEN - 1) { xwp += delta; xn = *(const float4*)xwp; }

    const char* hp = sb + (s & 1) * 256 + gq;         // broadcast per group
    v4i B0 = *(const v4i*)(hp);
    v4i B1 = *(const v4i*)(hp + 64);
    v4i B2 = *(const v4i*)(hp + 128);
    v4i B3 = *(const v4i*)(hp + 192);

    #pragma unroll
    for (int j = 0; j < 16; ++j) {
      v4i acc = mfma_i8(A[j][0], B0, vzero);
      acc = mfma_i8(A[j][1], B1, acc);
      acc = mfma_i8(A[j][2], B2, acc);
      acc = mfma_i8(A[j][3], B3, acc);
      if (prod) *(v4i*)(gtp + j * 64) = acc;          // write as soon as ready
    }
    wave_lds_fence();                                 // same-wave exchange

    v4i gv = *(const v4i*)grd;                        // (i,f,g,o) raw dots
    float gi = fmaf((float)gv.x, SCALE_INV, xc.x);
    float gf = fmaf((float)gv.y, SCALE_INV, xc.y);
    float gc = fmaf((float)gv.z, SCALE_INV, xc.z);
    float go = fmaf((float)gv.w, SCALE_INV, xc.w);
    gi = 1.f / (1.f + __expf(-gi));
    gf = 1.f / (1.f + __expf(-gf));
    go = 1.f / (1.f + __expf(-go));
    gc = 1.f - 2.f / (__expf(2.f * gc) + 1.f);        // tanh
    cst = gf * cst + gi * gc;
    float th = 1.f - 2.f / (__expf(2.f * cst) + 1.f);
    h = go * th;
    *hsp = h;                                         // no reader in-kernel
    hsp += hdelta;
    int hi = (int)rintf(h * HSCALE);                  // |h|<1
    H8b[((s + 1) & 1) * 256 + c] = (unsigned char)(hi & 255);

    block_sync_lds();                                 // ONE barrier per step
    xc = xn;
  }
}

// ---------- kernel 5: feats[t][n] = [hs_f ; hs_b]·W_out[n] + b_out[n] ----------
__global__ void feats_kernel(const float* __restrict__ hs,
                             const float* __restrict__ wout,
                             const float* __restrict__ bout,
                             float* __restrict__ feats) {
  __shared__ float lf[16 * 257];
  __shared__ float lb[16 * 257];
  const int tid = threadIdx.x;   // 128
  const int t0 = blockIdx.x * 16;
  for (int i = tid; i < 16 * 256; i += 128) {
    int r = i >> 8, k = i & 255;
    lf[r * 257 + k] = hs[(size_t)(t0 + r) * 256 + k];
    lb[r * 257 + k] = hs[(size_t)T_LEN * 256 + (size_t)(t0 + r) * 256 + k];
  }
  __syncthreads();
  const int tl = tid >> 3, n = tid & 7;
  if (n < 7) {
    float acc = bout[n];
    #pragma unroll 8
    for (int k = 0; k < 256; ++k) acc = fmaf(lf[tl * 257 + k], wout[n * 512 + k], acc);
    #pragma unroll 8
    for (int k = 0; k < 256; ++k) acc = fmaf(lb[tl * 257 + k], wout[n * 512 + 256 + k], acc);
    feats[(t0 + tl) * 7 + n] = acc;
  }
}

// ---------- kernel 6: Viterbi decode ----------
__global__ __launch_bounds__(256) void viterbi_kernel(
    const float* __restrict__ feats,
    const float* __restrict__ trans,
    float* __restrict__ out) {
  extern __shared__ char vsm[];
  float*         fe = (float*)vsm;                       // [T_LEN*7]
  unsigned char* bp = (unsigned char*)(vsm + 57344);     // [T_LEN][8]
  unsigned char* G  = (unsigned char*)(vsm + 73728);     // [32][8]
  unsigned char* bt = (unsigned char*)(vsm + 73984);     // [32]
  const int tid = threadIdx.x;

  for (int i = tid; i < T_LEN * 7; i += 256) fe[i] = feats[i];
  __syncthreads();

  if (tid < 64) {
    const int j  = tid;
    const int jc = (j < 7) ? j : 0;
    float Trow[7];
    #pragma unroll
    for (int i = 0; i < 7; ++i) Trow[i] = trans[jc * 7 + i];
    float fv = (j == 5) ? 0.0f : NEG;    // START = 5
    for (int t = 0; t < T_LEN; ++t) {
      float f0 = rdlane_f32(fv, 0), f1 = rdlane_f32(fv, 1), f2 = rdlane_f32(fv, 2),
            f3 = rdlane_f32(fv, 3), f4 = rdlane_f32(fv, 4), f5 = rdlane_f32(fv, 5),
            f6 = rdlane_f32(fv, 6);
      float v0 = f0 + Trow[0], v1 = f1 + Trow[1], v2 = f2 + Trow[2],
            v3 = f3 + Trow[3], v4 = f4 + Trow[4], v5 = f5 + Trow[5],
            v6 = f6 + Trow[6];
      bool c01 = v0 >= v1;  float m01 = c01 ? v0 : v1;  int i01 = c01 ? 0 : 1;
      bool c23 = v2 >= v3;  float m23 = c23 ? v2 : v3;  int i23 = c23 ? 2 : 3;
      bool c45 = v4 >= v5;  float m45 = c45 ? v4 : v5;  int i45 = c45 ? 4 : 5;
      bool cA  = m01 >= m23; float mA = cA ? m01 : m23; int iA = cA ? i01 : i23;
      bool cB  = m45 >= v6;  float mB = cB ? m45 : v6;  int iB = cB ? i45 : 6;
      bool cF  = mA >= mB;   float best = cF ? mA : mB; int bi = cF ? iA : iB;
      if (j < 7) bp[t * 8 + j] = (unsigned char)bi;
      fv = best + fe[t * 7 + jc];
    }
    float term = fv + trans[42 + jc];    // transitions[END=6][j]
    float best = rdlane_f32(term, 0); int btag = 0;
    #pragma unroll
    for (int i = 1; i < 7; ++i) {
      float ti = rdlane_f32(term, i);
      if (ti > best) { best = ti; btag = i; }
    }
    if (j == 0) {
      out[0] = best;
      bt[31] = (unsigned char)btag;      // tag at t = 2047
    }
  }
  __syncthreads();

  // Phase A: per-segment composed maps (32 segments x 7 entry tags)
  {
    const int s = tid >> 3, j = tid & 7;
    if (s < 32 && j < 7) {
      int g = j;
      for (int t = s * 64 + 63; t >= s * 64; --t) g = bp[t * 8 + g];
      G[s * 8 + j] = (unsigned char)g;
    }
  }
  __syncthreads();

  // Phase B: boundary tags, serial over 32 segments
  if (tid == 0) {
    int x = bt[31];
    for (int s = 31; s >= 1; --s) { x = G[s * 8 + x]; bt[s - 1] = (unsigned char)x; }
  }
  __syncthreads();

  // Phase C: parallel rewalk, one lane per segment
  if (tid < 32) {
    const int s = tid;
    int tag = bt[s];
    for (int t = s * 64 + 63; t >= s * 64; --t) {
      out[1 + t] = (float)tag;
      tag = bp[t * 8 + tag];
    }
  }
}

// ---------- host ----------
extern "C" void kernel_launch(void* const* d_in, const int* in_sizes, int n_in,
                              void* d_out, int out_size, void* d_ws, size_t ws_size,
                              hipStream_t stream) {
  const int*   words = (const int*)d_in[0];
  const float* embed = (const float*)d_in[1];
  const float* Wih_f = (const float*)d_in[2];
  const float* Whh_f = (const float*)d_in[3];
  const float* bih_f = (const float*)d_in[4];
  const float* bhh_f = (const float*)d_in[5];
  const float* Wih_b = (const float*)d_in[6];
  const float* Whh_b = (const float*)d_in[7];
  const float* bih_b = (const float*)d_in[8];
  const float* bhh_b = (const float*)d_in[9];
  const float* Wout  = (const float*)d_in[10];
  const float* bout  = (const float*)d_in[11];
  const float* trans = (const float*)d_in[12];
  const float* h0    = (const float*)d_in[13];
  const float* c0    = (const float*)d_in[14];

  float* ws = (float*)d_ws;
  float* XW = ws;                        // 2*2048*1024           = 4,194,304 f
  float* HS = ws + 4194304;              // 2*2048*256            = 1,048,576 f
  float* XS = ws + 5242880;              // 2048*256              =   524,288 f
  float* FE = ws + 5767168;              // 2048*7                =    14,336 f
  u32*   WP = (u32*)(ws + 5781504);      // 131,072 dwords (int8 A-fragments)

  pack_whh_i8<<<512, 256, 0, stream>>>(Whh_f, Whh_b, WP);
  gather_kernel<<<T_LEN, 256, 0, stream>>>(words, embed, XS);
  dim3 ggrid(T_LEN / 32, 1024 / 128, 2);
  gemm_xw<<<ggrid, 256, 0, stream>>>(XS, Wih_f, Wih_b, bih_f, bhh_f, bih_b, bhh_b, XW);
  lstm_seq<<<2, 256, 0, stream>>>(XW, HS, WP, h0, c0);
  feats_kernel<<<128, 128, 0, stream>>>(HS, Wout, bout, FE);
  viterbi_kernel<<<1, 256, 74048, stream>>>(FE, trans, (float*)d_out);
}